// Round 4
// baseline (267.036 us; speedup 1.0000x reference)
//
#include <hip/hip_runtime.h>
#include <stdint.h>

// Problem constants (B=16, T=1024, F=512, H=4, dk=128, kernel=11, pad 5/5)
#define SCALE_Q 0.08838834764831845f   // 1/sqrt(128)
#define LOG2E 1.4426950408889634f
#define NEGBIG -1e30f

typedef __attribute__((ext_vector_type(4))) float f32x4;
typedef __attribute__((ext_vector_type(16))) float f32x16;
typedef __attribute__((ext_vector_type(8))) short s16x8;
typedef __attribute__((ext_vector_type(4))) unsigned u32x4;

static __device__ __forceinline__ unsigned short f2bf(float f) {
  unsigned int u = __builtin_bit_cast(unsigned int, f);
  u += 0x7FFFu + ((u >> 16) & 1u);           // round-to-nearest-even
  return (unsigned short)(u >> 16);
}

static __device__ __forceinline__ unsigned cvt_pk_bf16(float lo, float hi) {
  unsigned r;
  asm("v_cvt_pk_bf16_f32 %0, %1, %2" : "=v"(r) : "v"(lo), "v"(hi));
  return r;
}

static __device__ __forceinline__ float xchg_max(float x) {
  float a = x, b = x;
  asm("v_permlane32_swap_b32 %0, %1" : "+v"(a), "+v"(b));
  return fmaxf(a, b);
}
static __device__ __forceinline__ float xchg_sum(float x) {
  float a = x, b = x;
  asm("v_permlane32_swap_b32 %0, %1" : "+v"(a), "+v"(b));
  return a + b;
}

static __device__ __forceinline__ float vmax16(const f32x16& v) {
  float a = fmaxf(fmaxf(fmaxf(v[0], v[1]), fmaxf(v[2], v[3])),
                  fmaxf(fmaxf(v[4], v[5]), fmaxf(v[6], v[7])));
  float b = fmaxf(fmaxf(fmaxf(v[8], v[9]), fmaxf(v[10], v[11])),
                  fmaxf(fmaxf(v[12], v[13]), fmaxf(v[14], v[15])));
  return fmaxf(a, b);
}

// async global->LDS, 16B per lane. LDS dest must be wave-uniform base (+lane*16 implicit).
static __device__ __forceinline__ void gload16(const void* g, void* l) {
  __builtin_amdgcn_global_load_lds(
      (const __attribute__((address_space(1))) void*)g,
      (__attribute__((address_space(3))) void*)l, 16, 0, 0);
}

// ---------------------------------------------------------------- convert x
__global__ void k_convert_x(const float* __restrict__ x, unsigned short* __restrict__ xb) {
  int i = (blockIdx.x * 256 + threadIdx.x) * 8;
  const float4* p = reinterpret_cast<const float4*>(x + i);
  float4 a = p[0], b = p[1];
  s16x8 o;
  o[0] = f2bf(a.x); o[1] = f2bf(a.y); o[2] = f2bf(a.z); o[3] = f2bf(a.w);
  o[4] = f2bf(b.x); o[5] = f2bf(b.y); o[6] = f2bf(b.z); o[7] = f2bf(b.w);
  *reinterpret_cast<s16x8*>(xb + i) = o;
}

// ------------------------------------------- transpose W [K=512][N] -> bf16 [N][512]
__global__ void k_transpose_bf(const float* __restrict__ w, unsigned short* __restrict__ wt, int Nd) {
  int gid = blockIdx.x * 256 + threadIdx.x;
  int n = gid >> 6;
  int k0 = (gid & 63) * 8;
  if (n >= Nd) return;
  s16x8 o;
#pragma unroll
  for (int j = 0; j < 8; ++j) o[j] = f2bf(w[(size_t)(k0 + j) * Nd + n]);
  *reinterpret_cast<s16x8*>(wt + (size_t)n * 512 + k0) = o;
}

// ---------------------------------------------------------------- GEMM core (m97 structure)
// A [M][512] bf16, Bt [N][512] bf16. 128x128 tile, BK=64, 4 waves (2x2), 16x16x32 MFMA.
// global_load_lds staging: linear LDS dest + inverse-XOR'd global source, XOR'd ds_read.
// MODE 0: qkv epilogue (scatter q,k,v,vT) + masked-row tile skip.  MODE 1: +bias+fsmn -> fp32.
template <int MODE>
__launch_bounds__(256, 3)
__global__ void k_gemm(const unsigned short* __restrict__ A,
                       const unsigned short* __restrict__ Bt,
                       const float* __restrict__ bias,
                       const float* __restrict__ fsmn,
                       const float* __restrict__ mask,
                       unsigned short* __restrict__ qs, unsigned short* __restrict__ kbuf,
                       float* __restrict__ vf, unsigned short* __restrict__ vt,
                       float* __restrict__ outp,
                       int tiles_m, int cpx) {
  __shared__ unsigned short a_lds[128 * 64];
  __shared__ unsigned short b_lds[128 * 64];
  int bid0 = blockIdx.x;
  int bid = (bid0 & 7) * cpx + (bid0 >> 3);   // XCD swizzle (grid % 8 == 0)
  int rb = bid % tiles_m, cb = bid / tiles_m;
  int tid = threadIdx.x;
  int w = tid >> 6, lane = tid & 63;
  int g = lane >> 4, ln = lane & 15;
  int wr = w >> 1, wc = w & 1;

  if constexpr (MODE == 0) {
    // K/V columns of fully-masked query rows are never read downstream: skip tile.
    if (cb >= 4) {
      int b = (rb * 128) >> 10, t0 = (rb * 128) & 1023;
      const float* mb = mask + b * 1024 + t0;
      float a0 = mb[lane * 2], a1 = mb[lane * 2 + 1];
      if (__ballot(a0 != 0.f || a1 != 0.f) == 0ull) return;
    }
  }

  int sr = lane >> 3;        // row within wave chunk (8 rows/wave/round)
  int sc = lane & 7;         // 16B-granule slot (8 per 128B row)

  f32x4 acc[4][4] = {};

  for (int kb0 = 0; kb0 < 512; kb0 += 64) {
#pragma unroll
    for (int it = 0; it < 4; ++it) {
      int r = it * 32 + w * 8 + sr;            // 0..127
      int cg = sc ^ (r & 7);                   // pre-swizzled global granule
      gload16(A + (size_t)(rb * 128 + r) * 512 + kb0 + cg * 8,
              a_lds + (it * 32 + w * 8) * 64);
      gload16(Bt + (size_t)(cb * 128 + r) * 512 + kb0 + cg * 8,
              b_lds + (it * 32 + w * 8) * 64);
    }
    __syncthreads();
#pragma unroll
    for (int kk = 0; kk < 2; ++kk) {
      s16x8 af[4], bf[4];
#pragma unroll
      for (int m = 0; m < 4; ++m) {
        int row = wr * 64 + m * 16 + ln;
        af[m] = *reinterpret_cast<const s16x8*>(a_lds + row * 64 + (((kk * 4 + g) ^ (row & 7)) * 8));
      }
#pragma unroll
      for (int n = 0; n < 4; ++n) {
        int row = wc * 64 + n * 16 + ln;
        bf[n] = *reinterpret_cast<const s16x8*>(b_lds + row * 64 + (((kk * 4 + g) ^ (row & 7)) * 8));
      }
#pragma unroll
      for (int m = 0; m < 4; ++m)
#pragma unroll
        for (int n = 0; n < 4; ++n)
          acc[m][n] = __builtin_amdgcn_mfma_f32_16x16x32_bf16(af[m], bf[n], acc[m][n], 0, 0, 0);
    }
    __syncthreads();
  }

  // epilogue
  int c0 = cb * 128;
  int R0 = rb * 128 + wr * 64;
#pragma unroll
  for (int m = 0; m < 4; ++m) {
#pragma unroll
    for (int n = 0; n < 4; ++n) {
      int col = c0 + wc * 64 + n * 16 + ln;
      int Rbase = R0 + m * 16 + g * 4;
      if constexpr (MODE == 0) {
        float bv = bias[col];
        int which = col >> 9;          // 0=q 1=k 2=v  (uniform per block)
        int h = (col >> 7) & 3;        // uniform per block
        int d = col & 127;
        int b = Rbase >> 10, t0 = Rbase & 1023;
        if (which == 2) {
          unsigned short pk[4];
#pragma unroll
          for (int r = 0; r < 4; ++r) {
            float v = acc[m][n][r] + bv;
            vf[(size_t)(Rbase + r) * 512 + (col - 1024)] = v;
            pk[r] = f2bf(v);
          }
          uint2 uv;
          uv.x = (unsigned)pk[0] | ((unsigned)pk[1] << 16);
          uv.y = (unsigned)pk[2] | ((unsigned)pk[3] << 16);
          *reinterpret_cast<uint2*>(vt + ((size_t)((b * 4 + h) * 128 + d)) * 1024 + t0) = uv;
        } else {
          unsigned short* dst = (which == 0) ? qs : kbuf;
          float sc2 = (which == 0) ? (SCALE_Q * LOG2E) : 1.0f;   // fold log2e for exp2 softmax
#pragma unroll
          for (int r = 0; r < 4; ++r) {
            int t = t0 + r;
            dst[((size_t)((b * 4 + h) * 1024 + t)) * 128 + d] = f2bf((acc[m][n][r] + bv) * sc2);
          }
        }
      } else {
        float bv = bias[col];
#pragma unroll
        for (int r = 0; r < 4; ++r) {
          size_t idx = (size_t)(Rbase + r) * 512 + col;
          outp[idx] = acc[m][n][r] + bv + fsmn[idx];
        }
      }
    }
  }
}

// ---------------------------------------------------------------- FSMN (depthwise conv + residual, fp32)
__launch_bounds__(256, 2)
__global__ void k_fsmn(const float* __restrict__ vf, const float* __restrict__ mask,
                       const float* __restrict__ wf, float* __restrict__ out) {
  __shared__ float inp[266 * 64];
  __shared__ float wl[64 * 13];
  int bid = blockIdx.x;
  int b = bid >> 5;
  int tt = (bid >> 3) & 3;
  int dt = bid & 7;
  int t0 = tt * 256, d0 = dt * 64;
  int tid = threadIdx.x;
  if (tid < 64) {
#pragma unroll
    for (int j = 0; j < 11; ++j) wl[tid * 13 + j] = wf[(d0 + tid) * 11 + j];
  }
  for (int idx = tid; idx < 266 * 64; idx += 256) {
    int r = idx >> 6, c = idx & 63;
    int t = t0 - 5 + r;
    float v = 0.f;
    if (t >= 0 && t < 1024) v = vf[((size_t)b * 1024 + t) * 512 + d0 + c] * mask[b * 1024 + t];
    inp[idx] = v;
  }
  __syncthreads();
  for (int idx = tid; idx < 256 * 64; idx += 256) {
    int tr = idx >> 6, c = idx & 63;
    int t = t0 + tr;
    float acc = inp[(tr + 5) * 64 + c];   // residual
#pragma unroll
    for (int j = 0; j < 11; ++j) acc += inp[(tr + j) * 64 + c] * wl[c * 13 + j];
    out[((size_t)b * 1024 + t) * 512 + d0 + c] = acc * mask[b * 1024 + t];
  }
}

// ---------------------------------------------------------------- flash attention
// Swapped-QK^T, in-register softmax, double-buffered K/V via global_load_lds with
// prefetch-under-compute (1 barrier per tile). 8 waves x 32 q = 256 q/block, KVBLK=128.
__launch_bounds__(512, 1)
__global__ void k_attn(const unsigned short* __restrict__ qs,
                       const unsigned short* __restrict__ kbuf,
                       const unsigned short* __restrict__ vt,
                       const float* __restrict__ mask,
                       unsigned short* __restrict__ ctx) {
  __shared__ unsigned short smem[2 * 32768];   // 128KB: buf{0,1} x {K 128x128 | V^T 128x128}

  int bid0 = blockIdx.x;
  int bid = (bid0 & 7) * 32 + (bid0 >> 3);     // XCD swizzle (256 blocks, 8 XCDs)
  int qc = bid & 3;
  int bh = bid >> 2;
  int b = bh >> 2, h = bh & 3;
  int tid = threadIdx.x;
  int w = tid >> 6, l = tid & 63;
  int half = l >> 5, lq = l & 31;

  const unsigned short* kbase = kbuf + (size_t)bh * 1024 * 128;
  const unsigned short* vtbase = vt + (size_t)bh * 128 * 1024;
  const float* mbase = mask + b * 1024;

  // Q fragments (B-operand): lane: q = lq, dk = c*16 + half*8 + j
  s16x8 aq[8];
  {
    const unsigned short* qrow = qs + ((size_t)bh * 1024 + qc * 256 + w * 32 + lq) * 128 + half * 8;
#pragma unroll
    for (int c = 0; c < 8; ++c)
      aq[c] = *reinterpret_cast<const s16x8*>(qrow + c * 16);
  }

  s16x8 bone = {};                        // B[k][q] = 1 at k==0
  bone[0] = (short)(half == 0 ? 0x3F80 : 0);

  f32x16 o[4] = {};                       // O^T tiles, d = dt*32 + rows
  float M = NEGBIG, L = 0.f;

  // active-KV bitmask (wave-uniform, same in all waves)
  unsigned amask = 0;
  for (int kb = 0; kb < 8; ++kb) {
    float m0 = mbase[kb * 128 + l];
    float m1 = mbase[kb * 128 + 64 + l];
    if (__ballot((m0 != 0.f) || (m1 != 0.f)) != 0ull) amask |= (1u << kb);
  }

  // stage one KV tile into buffer bsel (8 x global_load_lds per wave)
  auto stage = [&](int kb, int bsel) {
    unsigned short* kd = smem + bsel * 32768;
    unsigned short* vd = kd + 16384;
    int srl = l >> 4;                     // 4 rows per wave per round
    int scl = l & 15;
#pragma unroll
    for (int it = 0; it < 4; ++it) {
      int r0 = it * 32 + w * 4;           // wave-uniform row base
      int r = r0 + srl;
      int cg = scl ^ (r & 15);            // pre-swizzled global granule
      gload16(kbase + (size_t)(kb * 128 + r) * 128 + cg * 8, kd + r0 * 128);
      gload16(vtbase + (size_t)r * 1024 + kb * 128 + cg * 8, vd + r0 * 128);
    }
  };

  unsigned rem = amask;
  int kb_cur = __ffs(rem) - 1; rem &= rem - 1;
  stage(kb_cur, 0);
  __syncthreads();                        // buf0 ready
  int cur = 0;

  while (true) {
    int kb_next = rem ? (__ffs(rem) - 1) : -1;
    if (kb_next >= 0) { rem &= rem - 1; stage(kb_next, cur ^ 1); }  // flies under compute

    unsigned short* kl = smem + cur * 32768;
    unsigned short* vl = kl + 16384;

    // ---- QK^T: 4 tiles of S^T[32k][32q]; bias-MFMA injects -BIG at masked k
    f32x16 s[4];
    __builtin_amdgcn_s_setprio(1);
#pragma unroll
    for (int kt = 0; kt < 4; ++kt) {
      float mv = mbase[kb_cur * 128 + kt * 32 + lq];
      s16x8 ba = {};
      ba[0] = (short)((half == 0 && mv == 0.f) ? (short)0xFF7F : 0);  // bf16 -3.39e38
      f32x16 z = {};
      s[kt] = __builtin_amdgcn_mfma_f32_32x32x16_bf16(ba, bone, z, 0, 0, 0);
      int row = kt * 32 + lq, rx = row & 15;
#pragma unroll
      for (int c = 0; c < 8; ++c) {
        s16x8 kf = *reinterpret_cast<const s16x8*>(kl + row * 128 + (((c * 2 + half) ^ rx) * 8));
        s[kt] = __builtin_amdgcn_mfma_f32_32x32x16_bf16(kf, aq[c], s[kt], 0, 0, 0);
      }
    }
    __builtin_amdgcn_s_setprio(0);

    // ---- online softmax (log2 domain; per-lane scalar M/L for q = lq)
    float mx = fmaxf(fmaxf(vmax16(s[0]), vmax16(s[1])), fmaxf(vmax16(s[2]), vmax16(s[3])));
    mx = xchg_max(mx);
    float mnew = fmaxf(M, mx);
    float alpha = exp2f(M - mnew);
    M = mnew;
    float ls0 = 0.f, ls1 = 0.f, ls2 = 0.f, ls3 = 0.f;
#pragma unroll
    for (int kt = 0; kt < 4; ++kt) {
#pragma unroll
      for (int i = 0; i < 16; ++i) {
        float p = exp2f(s[kt][i] - M);
        s[kt][i] = p;
        if ((i & 3) == 0) ls0 += p; else if ((i & 3) == 1) ls1 += p;
        else if ((i & 3) == 2) ls2 += p; else ls3 += p;
      }
    }
    float ls = (ls0 + ls1) + (ls2 + ls3);
    ls = xchg_sum(ls);
    L = L * alpha + ls;
#pragma unroll
    for (int dt = 0; dt < 4; ++dt)
#pragma unroll
      for (int i = 0; i < 16; ++i) o[dt][i] *= alpha;

    // ---- pack P^T into B-frags (cvt_pk + permlane32_swap), PV per kt
    __builtin_amdgcn_s_setprio(1);
#pragma unroll
    for (int kt = 0; kt < 4; ++kt) {
      unsigned w0 = cvt_pk_bf16(s[kt][0], s[kt][1]);
      unsigned w1 = cvt_pk_bf16(s[kt][2], s[kt][3]);
      unsigned w2 = cvt_pk_bf16(s[kt][4], s[kt][5]);
      unsigned w3 = cvt_pk_bf16(s[kt][6], s[kt][7]);
      unsigned w4 = cvt_pk_bf16(s[kt][8], s[kt][9]);
      unsigned w5 = cvt_pk_bf16(s[kt][10], s[kt][11]);
      unsigned w6 = cvt_pk_bf16(s[kt][12], s[kt][13]);
      unsigned w7 = cvt_pk_bf16(s[kt][14], s[kt][15]);
      asm("v_permlane32_swap_b32 %0, %1" : "+v"(w0), "+v"(w2));
      asm("v_permlane32_swap_b32 %0, %1" : "+v"(w1), "+v"(w3));
      asm("v_permlane32_swap_b32 %0, %1" : "+v"(w4), "+v"(w6));
      asm("v_permlane32_swap_b32 %0, %1" : "+v"(w5), "+v"(w7));
      u32x4 f0 = {w0, w1, w2, w3};
      u32x4 f1 = {w4, w5, w6, w7};
      s16x8 p0 = __builtin_bit_cast(s16x8, f0);   // k = kt*32 + 0..15
      s16x8 p1 = __builtin_bit_cast(s16x8, f1);   // k = kt*32 + 16..31
#pragma unroll
      for (int dt = 0; dt < 4; ++dt) {
        int row = dt * 32 + lq, rx = row & 15;
        s16x8 va = *reinterpret_cast<const s16x8*>(vl + row * 128 + (((kt * 4 + half) ^ rx) * 8));
        o[dt] = __builtin_amdgcn_mfma_f32_32x32x16_bf16(va, p0, o[dt], 0, 0, 0);
        s16x8 vb = *reinterpret_cast<const s16x8*>(vl + row * 128 + (((kt * 4 + 2 + half) ^ rx) * 8));
        o[dt] = __builtin_amdgcn_mfma_f32_32x32x16_bf16(vb, p1, o[dt], 0, 0, 0);
      }
    }
    __builtin_amdgcn_s_setprio(0);

    if (kb_next < 0) break;
    __syncthreads();                      // next buf staged; readers of cur done
    kb_cur = kb_next; cur ^= 1;
  }

  // ---- epilogue: O^T -> LDS transpose -> coalesced ctx write
  float inv = 1.0f / L;
  __syncthreads();
  unsigned short* obuf = smem;            // [256 q][128 d] bf16, 8B-granule XOR (row&15)
#pragma unroll
  for (int dt = 0; dt < 4; ++dt) {
#pragma unroll
    for (int g = 0; g < 4; ++g) {
      int d0 = dt * 32 + g * 8 + half * 4;
      unsigned lo = cvt_pk_bf16(o[dt][g * 4 + 0] * inv, o[dt][g * 4 + 1] * inv);
      unsigned hi = cvt_pk_bf16(o[dt][g * 4 + 2] * inv, o[dt][g * 4 + 3] * inv);
      int row = w * 32 + lq;
      int gr = d0 >> 2;
      uint2 uv; uv.x = lo; uv.y = hi;
      *reinterpret_cast<uint2*>(obuf + row * 128 + ((gr ^ (row & 15)) * 4)) = uv;
    }
  }
  __syncthreads();
  size_t cbase = ((size_t)b * 1024 + qc * 256) * 512 + h * 128;
#pragma unroll
  for (int it = 0; it < 16; ++it) {
    int chunk = it * 512 + tid;
    int row = chunk >> 5, gr = chunk & 31;
    uint2 v = *reinterpret_cast<uint2*>(obuf + row * 128 + ((gr ^ (row & 15)) * 4));
    *reinterpret_cast<uint2*>(ctx + cbase + (size_t)row * 512 + gr * 4) = v;
  }
}

// ---------------------------------------------------------------- launch
extern "C" void kernel_launch(void* const* d_in, const int* in_sizes, int n_in,
                              void* d_out, int out_size, void* d_ws, size_t ws_size,
                              hipStream_t stream) {
  const float* x      = (const float*)d_in[0];
  const float* mask   = (const float*)d_in[1];
  const float* w_qkv  = (const float*)d_in[2];
  const float* b_qkv  = (const float*)d_in[3];
  const float* w_out  = (const float*)d_in[4];
  const float* b_out  = (const float*)d_in[5];
  const float* w_fsmn = (const float*)d_in[6];
  float* out = (float*)d_out;

  char* ws = (char*)d_ws;
  size_t off = 0;
  auto alloc = [&](size_t bytes) { void* p = ws + off; off += (bytes + 255) & ~(size_t)255; return p; };
  unsigned short* x_bf   = (unsigned short*)alloc(16384ull * 512 * 2);
  unsigned short* wT_qkv = (unsigned short*)alloc(1536ull * 512 * 2);
  unsigned short* wT_out = (unsigned short*)alloc(512ull * 512 * 2);
  unsigned short* qs     = (unsigned short*)alloc(64ull * 1024 * 128 * 2);
  unsigned short* kbuf   = (unsigned short*)alloc(64ull * 1024 * 128 * 2);
  unsigned short* vt     = (unsigned short*)alloc(64ull * 128 * 1024 * 2);
  float*          vf     = (float*)alloc(16384ull * 512 * 4);
  float*          fsmn   = (float*)alloc(16384ull * 512 * 4);
  unsigned short* ctx    = (unsigned short*)alloc(16384ull * 512 * 2);

  k_convert_x<<<4096, 256, 0, stream>>>(x, x_bf);
  k_transpose_bf<<<(1536 * 64) / 256, 256, 0, stream>>>(w_qkv, wT_qkv, 1536);
  k_transpose_bf<<<(512 * 64) / 256, 256, 0, stream>>>(w_out, wT_out, 512);
  k_gemm<0><<<128 * 12, 256, 0, stream>>>(x_bf, wT_qkv, b_qkv, nullptr, mask,
                                          qs, kbuf, vf, vt, nullptr, 128, (128 * 12) / 8);
  k_fsmn<<<512, 256, 0, stream>>>(vf, mask, w_fsmn, fsmn);
  k_attn<<<256, 512, 0, stream>>>(qs, kbuf, vt, mask, ctx);
  k_gemm<1><<<128 * 4, 256, 0, stream>>>(ctx, wT_out, b_out, fsmn, nullptr,
                                         nullptr, nullptr, nullptr, nullptr, out, 128, (128 * 4) / 8);
}

// Round 5
// 204.981 us; speedup vs baseline: 1.3027x; 1.3027x over previous
//
#include <hip/hip_runtime.h>
#include <stdint.h>

// Problem constants (B=16, T=1024, F=512, H=4, dk=128, kernel=11, pad 5/5)
#define SCALE_Q 0.08838834764831845f   // 1/sqrt(128)
#define LOG2E 1.4426950408889634f
#define NEGBIG -1e30f

typedef __attribute__((ext_vector_type(4))) float f32x4;
typedef __attribute__((ext_vector_type(16))) float f32x16;
typedef __attribute__((ext_vector_type(8))) short s16x8;
typedef __attribute__((ext_vector_type(4))) unsigned u32x4;

static __device__ __forceinline__ unsigned short f2bf(float f) {
  unsigned int u = __builtin_bit_cast(unsigned int, f);
  u += 0x7FFFu + ((u >> 16) & 1u);           // round-to-nearest-even
  return (unsigned short)(u >> 16);
}
static __device__ __forceinline__ float bf2f(unsigned short b) {
  unsigned int u = ((unsigned int)b) << 16;
  return __builtin_bit_cast(float, u);
}

static __device__ __forceinline__ unsigned cvt_pk_bf16(float lo, float hi) {
  unsigned r;
  asm("v_cvt_pk_bf16_f32 %0, %1, %2" : "=v"(r) : "v"(lo), "v"(hi));
  return r;
}

static __device__ __forceinline__ float xchg_max(float x) {
  float a = x, b = x;
  asm("v_permlane32_swap_b32 %0, %1" : "+v"(a), "+v"(b));
  return fmaxf(a, b);
}
static __device__ __forceinline__ float xchg_sum(float x) {
  float a = x, b = x;
  asm("v_permlane32_swap_b32 %0, %1" : "+v"(a), "+v"(b));
  return a + b;
}

static __device__ __forceinline__ float vmax16(const f32x16& v) {
  float a = fmaxf(fmaxf(fmaxf(v[0], v[1]), fmaxf(v[2], v[3])),
                  fmaxf(fmaxf(v[4], v[5]), fmaxf(v[6], v[7])));
  float b = fmaxf(fmaxf(fmaxf(v[8], v[9]), fmaxf(v[10], v[11])),
                  fmaxf(fmaxf(v[12], v[13]), fmaxf(v[14], v[15])));
  return fmaxf(a, b);
}

// async global->LDS, 16B per lane. LDS dest must be wave-uniform base (+lane*16 implicit).
static __device__ __forceinline__ void gload16(const void* g, void* l) {
  __builtin_amdgcn_global_load_lds(
      (const __attribute__((address_space(1))) void*)g,
      (__attribute__((address_space(3))) void*)l, 16, 0, 0);
}

// ---------------------------------------------------------------- convert x
__global__ void k_convert_x(const float* __restrict__ x, unsigned short* __restrict__ xb) {
  int i = (blockIdx.x * 256 + threadIdx.x) * 8;
  const float4* p = reinterpret_cast<const float4*>(x + i);
  float4 a = p[0], b = p[1];
  s16x8 o;
  o[0] = f2bf(a.x); o[1] = f2bf(a.y); o[2] = f2bf(a.z); o[3] = f2bf(a.w);
  o[4] = f2bf(b.x); o[5] = f2bf(b.y); o[6] = f2bf(b.z); o[7] = f2bf(b.w);
  *reinterpret_cast<s16x8*>(xb + i) = o;
}

// ------------------------------------------- transpose W [K=512][N] -> bf16 [N][512]
__global__ void k_transpose_bf(const float* __restrict__ w, unsigned short* __restrict__ wt, int Nd) {
  int gid = blockIdx.x * 256 + threadIdx.x;
  int n = gid >> 6;
  int k0 = (gid & 63) * 8;
  if (n >= Nd) return;
  s16x8 o;
#pragma unroll
  for (int j = 0; j < 8; ++j) o[j] = f2bf(w[(size_t)(k0 + j) * Nd + n]);
  *reinterpret_cast<s16x8*>(wt + (size_t)n * 512 + k0) = o;
}

// ---------------------------------------------------------------- GEMM core
// A [M][512] bf16, Bt [N][512] bf16. 128x128 tile, BK=64, 4 waves (2x2), 16x16x32 MFMA.
// Double-buffered global_load_lds with prefetch-under-compute (1 barrier per K-step).
// Block mapping rb-major (rb = bid/tiles_n): each XCD owns a contiguous rb slice
// across ALL column tiles -> A-slice (2MB) + B reside in the per-XCD L2.
// MODE 0: qkv epilogue (scatter q,k,v_bf16,vT) + masked-row tile skip.
// MODE 1: out epilogue (+bias + FUSED FSMN depthwise conv + residual -> fp32).
template <int MODE>
__launch_bounds__(256, 2)
__global__ void k_gemm(const unsigned short* __restrict__ A,
                       const unsigned short* __restrict__ Bt,
                       const float* __restrict__ bias,
                       const float* __restrict__ mask,
                       const float* __restrict__ wf,      // w_fsmn (MODE 1)
                       const unsigned short* __restrict__ vsrc, // v bf16 [b,t,d] (MODE 1)
                       unsigned short* __restrict__ qs, unsigned short* __restrict__ kbuf,
                       unsigned short* __restrict__ vbf, unsigned short* __restrict__ vt,
                       float* __restrict__ outp,
                       int tiles_n, int cpx) {
  __shared__ unsigned short smem[32768];     // 64KB: 2 bufs x (A 16KB | B 16KB)
  int bid0 = blockIdx.x;
  int bid = (bid0 & 7) * cpx + (bid0 >> 3);  // XCD swizzle (grid % 8 == 0)
  int rb = bid / tiles_n, cb = bid % tiles_n;
  int tid = threadIdx.x;
  int w = tid >> 6, lane = tid & 63;
  int g = lane >> 4, ln = lane & 15;
  int wr = w >> 1, wc = w & 1;

  if constexpr (MODE == 0) {
    // K/V columns of fully-masked query rows are never read downstream: skip tile.
    if (cb >= 4) {
      int b = (rb * 128) >> 10, t0 = (rb * 128) & 1023;
      const float* mb = mask + b * 1024 + t0;
      float a0 = mb[lane * 2], a1 = mb[lane * 2 + 1];
      if (__ballot(a0 != 0.f || a1 != 0.f) == 0ull) return;
    }
  }

  int sr = lane >> 3;        // row within wave chunk (8 rows/wave/round)
  int sc = lane & 7;         // 16B-granule slot (8 per 128B row)

  // stage one BK=64 K-slab of A and B into buffer bsel
  auto stage = [&](int kb0, int bsel) {
    unsigned short* al = smem + bsel * 16384;
    unsigned short* bl = al + 8192;
#pragma unroll
    for (int it = 0; it < 4; ++it) {
      int r0 = it * 32 + w * 8;                // wave-uniform row base
      int r = r0 + sr;
      int cg = sc ^ (r & 7);                   // pre-swizzled global granule
      gload16(A + (size_t)(rb * 128 + r) * 512 + kb0 + cg * 8, al + r0 * 64);
      gload16(Bt + (size_t)(cb * 128 + r) * 512 + kb0 + cg * 8, bl + r0 * 64);
    }
  };

  f32x4 acc[4][4] = {};

  stage(0, 0);
  __syncthreads();                             // buf0 ready
  int cur = 0;
  for (int kt = 0; kt < 8; ++kt) {
    if (kt < 7) stage((kt + 1) * 64, cur ^ 1); // flies under compute
    const unsigned short* al = smem + cur * 16384;
    const unsigned short* bl = al + 8192;
#pragma unroll
    for (int kk = 0; kk < 2; ++kk) {
      s16x8 af[4], bf[4];
#pragma unroll
      for (int m = 0; m < 4; ++m) {
        int row = wr * 64 + m * 16 + ln;
        af[m] = *reinterpret_cast<const s16x8*>(al + row * 64 + (((kk * 4 + g) ^ (row & 7)) * 8));
      }
#pragma unroll
      for (int n = 0; n < 4; ++n) {
        int row = wc * 64 + n * 16 + ln;
        bf[n] = *reinterpret_cast<const s16x8*>(bl + row * 64 + (((kk * 4 + g) ^ (row & 7)) * 8));
      }
#pragma unroll
      for (int m = 0; m < 4; ++m)
#pragma unroll
        for (int n = 0; n < 4; ++n)
          acc[m][n] = __builtin_amdgcn_mfma_f32_16x16x32_bf16(af[m], bf[n], acc[m][n], 0, 0, 0);
    }
    __syncthreads();                           // next buf staged; readers of cur done
    cur ^= 1;
  }

  int c0 = cb * 128;
  int R0 = rb * 128 + wr * 64;

  if constexpr (MODE == 0) {
#pragma unroll
    for (int m = 0; m < 4; ++m) {
#pragma unroll
      for (int n = 0; n < 4; ++n) {
        int col = c0 + wc * 64 + n * 16 + ln;
        int Rbase = R0 + m * 16 + g * 4;
        float bv = bias[col];
        int which = col >> 9;          // 0=q 1=k 2=v  (uniform per block)
        int h = (col >> 7) & 3;        // uniform per block
        int d = col & 127;
        int b = Rbase >> 10, t0 = Rbase & 1023;
        if (which == 2) {
          unsigned short pk[4];
#pragma unroll
          for (int r = 0; r < 4; ++r) {
            float v = acc[m][n][r] + bv;
            pk[r] = f2bf(v);
            vbf[(size_t)(Rbase + r) * 512 + (col - 1024)] = pk[r];
          }
          uint2 uv;
          uv.x = (unsigned)pk[0] | ((unsigned)pk[1] << 16);
          uv.y = (unsigned)pk[2] | ((unsigned)pk[3] << 16);
          *reinterpret_cast<uint2*>(vt + ((size_t)((b * 4 + h) * 128 + d)) * 1024 + t0) = uv;
        } else {
          unsigned short* dst = (which == 0) ? qs : kbuf;
          float sc2 = (which == 0) ? (SCALE_Q * LOG2E) : 1.0f;   // fold log2e for exp2 softmax
#pragma unroll
          for (int r = 0; r < 4; ++r) {
            int t = t0 + r;
            dst[((size_t)((b * 4 + h) * 1024 + t)) * 128 + d] = f2bf((acc[m][n][r] + bv) * sc2);
          }
        }
      }
    }
  } else {
    // ---- fused FSMN: stage masked v-halo [138][128] (stride 136, 16B-aligned rows)
    // and per-col taps, then out = acc + bias + (conv11 + resid) * mask.
    int b = (rb * 128) >> 10, tloc0 = (rb * 128) & 1023;
    unsigned short* vh = smem;                         // 138*136 u16 = 37.5KB
    float* wl = reinterpret_cast<float*>(smem + 18816); // 128*11 f32 = 5.6KB
    for (int idx = tid; idx < 138 * 16; idx += 256) {
      int i = idx >> 4, gc = idx & 15;
      int tl = tloc0 - 5 + i;
      s16x8 v8 = {};
      if (tl >= 0 && tl < 1024) {
        if (mask[b * 1024 + tl] != 0.f)
          v8 = *reinterpret_cast<const s16x8*>(vsrc + ((size_t)b * 1024 + tl) * 512 + c0 + gc * 8);
      }
      *reinterpret_cast<s16x8*>(vh + i * 136 + gc * 8) = v8;
    }
    if (tid < 128) {
#pragma unroll
      for (int j = 0; j < 11; ++j) wl[tid * 11 + j] = wf[(c0 + tid) * 11 + j];
    }
    __syncthreads();

#pragma unroll
    for (int m = 0; m < 4; ++m) {
      int Rbase = R0 + m * 16 + g * 4;
      int lrb = Rbase - rb * 128;          // local row base, 0..124
      float mk[4];
#pragma unroll
      for (int r = 0; r < 4; ++r) mk[r] = mask[b * 1024 + ((Rbase + r) & 1023)];
#pragma unroll
      for (int n = 0; n < 4; ++n) {
        int lc = wc * 64 + n * 16 + ln;
        int col = c0 + lc;
        float bv = bias[col];
        float win[14];
#pragma unroll
        for (int i = 0; i < 14; ++i) win[i] = bf2f(vh[(lrb + i) * 136 + lc]);
        float wj[11];
#pragma unroll
        for (int j = 0; j < 11; ++j) wj[j] = wl[lc * 11 + j];
#pragma unroll
        for (int r = 0; r < 4; ++r) {
          float conv = win[r + 5];         // residual
#pragma unroll
          for (int j = 0; j < 11; ++j) conv += wj[j] * win[r + j];
          size_t idx = (size_t)(Rbase + r) * 512 + col;
          outp[idx] = acc[m][n][r] + bv + conv * mk[r];
        }
      }
    }
  }
}

// ---------------------------------------------------------------- flash attention
// Swapped-QK^T, in-register softmax, double-buffered K/V via global_load_lds with
// prefetch-under-compute (1 barrier per tile). 8 waves x 32 q = 256 q/block, KVBLK=128.
__launch_bounds__(512, 1)
__global__ void k_attn(const unsigned short* __restrict__ qs,
                       const unsigned short* __restrict__ kbuf,
                       const unsigned short* __restrict__ vt,
                       const float* __restrict__ mask,
                       unsigned short* __restrict__ ctx) {
  __shared__ unsigned short smem[2 * 32768];   // 128KB: buf{0,1} x {K 128x128 | V^T 128x128}

  int bid0 = blockIdx.x;
  int bid = (bid0 & 7) * 32 + (bid0 >> 3);     // XCD swizzle (256 blocks, 8 XCDs)
  int qc = bid & 3;
  int bh = bid >> 2;
  int b = bh >> 2, h = bh & 3;
  int tid = threadIdx.x;
  int w = tid >> 6, l = tid & 63;
  int half = l >> 5, lq = l & 31;

  const unsigned short* kbase = kbuf + (size_t)bh * 1024 * 128;
  const unsigned short* vtbase = vt + (size_t)bh * 128 * 1024;
  const float* mbase = mask + b * 1024;

  // Q fragments (B-operand): lane: q = lq, dk = c*16 + half*8 + j
  s16x8 aq[8];
  {
    const unsigned short* qrow = qs + ((size_t)bh * 1024 + qc * 256 + w * 32 + lq) * 128 + half * 8;
#pragma unroll
    for (int c = 0; c < 8; ++c)
      aq[c] = *reinterpret_cast<const s16x8*>(qrow + c * 16);
  }

  s16x8 bone = {};                        // B[k][q] = 1 at k==0
  bone[0] = (short)(half == 0 ? 0x3F80 : 0);

  f32x16 o[4] = {};                       // O^T tiles, d = dt*32 + rows
  float M = NEGBIG, L = 0.f;

  // active-KV bitmask (wave-uniform, same in all waves)
  unsigned amask = 0;
  for (int kb = 0; kb < 8; ++kb) {
    float m0 = mbase[kb * 128 + l];
    float m1 = mbase[kb * 128 + 64 + l];
    if (__ballot((m0 != 0.f) || (m1 != 0.f)) != 0ull) amask |= (1u << kb);
  }

  // stage one KV tile into buffer bsel (8 x global_load_lds per wave)
  auto stage = [&](int kb, int bsel) {
    unsigned short* kd = smem + bsel * 32768;
    unsigned short* vd = kd + 16384;
    int srl = l >> 4;                     // 4 rows per wave per round
    int scl = l & 15;
#pragma unroll
    for (int it = 0; it < 4; ++it) {
      int r0 = it * 32 + w * 4;           // wave-uniform row base
      int r = r0 + srl;
      int cg = scl ^ (r & 15);            // pre-swizzled global granule
      gload16(kbase + (size_t)(kb * 128 + r) * 128 + cg * 8, kd + r0 * 128);
      gload16(vtbase + (size_t)r * 1024 + kb * 128 + cg * 8, vd + r0 * 128);
    }
  };

  unsigned rem = amask;
  int kb_cur = __ffs(rem) - 1; rem &= rem - 1;
  stage(kb_cur, 0);
  __syncthreads();                        // buf0 ready
  int cur = 0;

  while (true) {
    int kb_next = rem ? (__ffs(rem) - 1) : -1;
    if (kb_next >= 0) { rem &= rem - 1; stage(kb_next, cur ^ 1); }  // flies under compute

    unsigned short* kl = smem + cur * 32768;
    unsigned short* vl = kl + 16384;

    // ---- QK^T: 4 tiles of S^T[32k][32q]; bias-MFMA injects -BIG at masked k
    f32x16 s[4];
    __builtin_amdgcn_s_setprio(1);
#pragma unroll
    for (int kt = 0; kt < 4; ++kt) {
      float mv = mbase[kb_cur * 128 + kt * 32 + lq];
      s16x8 ba = {};
      ba[0] = (short)((half == 0 && mv == 0.f) ? (short)0xFF7F : 0);  // bf16 -3.39e38
      f32x16 z = {};
      s[kt] = __builtin_amdgcn_mfma_f32_32x32x16_bf16(ba, bone, z, 0, 0, 0);
      int row = kt * 32 + lq, rx = row & 15;
#pragma unroll
      for (int c = 0; c < 8; ++c) {
        s16x8 kf = *reinterpret_cast<const s16x8*>(kl + row * 128 + (((c * 2 + half) ^ rx) * 8));
        s[kt] = __builtin_amdgcn_mfma_f32_32x32x16_bf16(kf, aq[c], s[kt], 0, 0, 0);
      }
    }
    __builtin_amdgcn_s_setprio(0);

    // ---- online softmax (log2 domain; per-lane scalar M/L for q = lq)
    float mx = fmaxf(fmaxf(vmax16(s[0]), vmax16(s[1])), fmaxf(vmax16(s[2]), vmax16(s[3])));
    mx = xchg_max(mx);
    float mnew = fmaxf(M, mx);
    float alpha = exp2f(M - mnew);
    M = mnew;
    float ls0 = 0.f, ls1 = 0.f, ls2 = 0.f, ls3 = 0.f;
#pragma unroll
    for (int kt = 0; kt < 4; ++kt) {
#pragma unroll
      for (int i = 0; i < 16; ++i) {
        float p = exp2f(s[kt][i] - M);
        s[kt][i] = p;
        if ((i & 3) == 0) ls0 += p; else if ((i & 3) == 1) ls1 += p;
        else if ((i & 3) == 2) ls2 += p; else ls3 += p;
      }
    }
    float ls = (ls0 + ls1) + (ls2 + ls3);
    ls = xchg_sum(ls);
    L = L * alpha + ls;
#pragma unroll
    for (int dt = 0; dt < 4; ++dt)
#pragma unroll
      for (int i = 0; i < 16; ++i) o[dt][i] *= alpha;

    // ---- pack P^T into B-frags (cvt_pk + permlane32_swap), PV per kt
    __builtin_amdgcn_s_setprio(1);
#pragma unroll
    for (int kt = 0; kt < 4; ++kt) {
      unsigned w0 = cvt_pk_bf16(s[kt][0], s[kt][1]);
      unsigned w1 = cvt_pk_bf16(s[kt][2], s[kt][3]);
      unsigned w2 = cvt_pk_bf16(s[kt][4], s[kt][5]);
      unsigned w3 = cvt_pk_bf16(s[kt][6], s[kt][7]);
      unsigned w4 = cvt_pk_bf16(s[kt][8], s[kt][9]);
      unsigned w5 = cvt_pk_bf16(s[kt][10], s[kt][11]);
      unsigned w6 = cvt_pk_bf16(s[kt][12], s[kt][13]);
      unsigned w7 = cvt_pk_bf16(s[kt][14], s[kt][15]);
      asm("v_permlane32_swap_b32 %0, %1" : "+v"(w0), "+v"(w2));
      asm("v_permlane32_swap_b32 %0, %1" : "+v"(w1), "+v"(w3));
      asm("v_permlane32_swap_b32 %0, %1" : "+v"(w4), "+v"(w6));
      asm("v_permlane32_swap_b32 %0, %1" : "+v"(w5), "+v"(w7));
      u32x4 f0 = {w0, w1, w2, w3};
      u32x4 f1 = {w4, w5, w6, w7};
      s16x8 p0 = __builtin_bit_cast(s16x8, f0);   // k = kt*32 + 0..15
      s16x8 p1 = __builtin_bit_cast(s16x8, f1);   // k = kt*32 + 16..31
#pragma unroll
      for (int dt = 0; dt < 4; ++dt) {
        int row = dt * 32 + lq, rx = row & 15;
        s16x8 va = *reinterpret_cast<const s16x8*>(vl + row * 128 + (((kt * 4 + half) ^ rx) * 8));
        o[dt] = __builtin_amdgcn_mfma_f32_32x32x16_bf16(va, p0, o[dt], 0, 0, 0);
        s16x8 vb = *reinterpret_cast<const s16x8*>(vl + row * 128 + (((kt * 4 + 2 + half) ^ rx) * 8));
        o[dt] = __builtin_amdgcn_mfma_f32_32x32x16_bf16(vb, p1, o[dt], 0, 0, 0);
      }
    }
    __builtin_amdgcn_s_setprio(0);

    if (kb_next < 0) break;
    __syncthreads();                      // next buf staged; readers of cur done
    kb_cur = kb_next; cur ^= 1;
  }

  // ---- epilogue: O^T -> LDS transpose -> coalesced ctx write
  float inv = 1.0f / L;
  __syncthreads();
  unsigned short* obuf = smem;            // [256 q][128 d] bf16, 8B-granule XOR (row&15)
#pragma unroll
  for (int dt = 0; dt < 4; ++dt) {
#pragma unroll
    for (int g = 0; g < 4; ++g) {
      int d0 = dt * 32 + g * 8 + half * 4;
      unsigned lo = cvt_pk_bf16(o[dt][g * 4 + 0] * inv, o[dt][g * 4 + 1] * inv);
      unsigned hi = cvt_pk_bf16(o[dt][g * 4 + 2] * inv, o[dt][g * 4 + 3] * inv);
      int row = w * 32 + lq;
      int gr = d0 >> 2;
      uint2 uv; uv.x = lo; uv.y = hi;
      *reinterpret_cast<uint2*>(obuf + row * 128 + ((gr ^ (row & 15)) * 4)) = uv;
    }
  }
  __syncthreads();
  size_t cbase = ((size_t)b * 1024 + qc * 256) * 512 + h * 128;
#pragma unroll
  for (int it = 0; it < 16; ++it) {
    int chunk = it * 512 + tid;
    int row = chunk >> 5, gr = chunk & 31;
    uint2 v = *reinterpret_cast<uint2*>(obuf + row * 128 + ((gr ^ (row & 15)) * 4));
    *reinterpret_cast<uint2*>(ctx + cbase + (size_t)row * 512 + gr * 4) = v;
  }
}

// ---------------------------------------------------------------- launch
extern "C" void kernel_launch(void* const* d_in, const int* in_sizes, int n_in,
                              void* d_out, int out_size, void* d_ws, size_t ws_size,
                              hipStream_t stream) {
  const float* x      = (const float*)d_in[0];
  const float* mask   = (const float*)d_in[1];
  const float* w_qkv  = (const float*)d_in[2];
  const float* b_qkv  = (const float*)d_in[3];
  const float* w_out  = (const float*)d_in[4];
  const float* b_out  = (const float*)d_in[5];
  const float* w_fsmn = (const float*)d_in[6];
  float* out = (float*)d_out;

  char* ws = (char*)d_ws;
  size_t off = 0;
  auto alloc = [&](size_t bytes) { void* p = ws + off; off += (bytes + 255) & ~(size_t)255; return p; };
  unsigned short* x_bf   = (unsigned short*)alloc(16384ull * 512 * 2);
  unsigned short* wT_qkv = (unsigned short*)alloc(1536ull * 512 * 2);
  unsigned short* wT_out = (unsigned short*)alloc(512ull * 512 * 2);
  unsigned short* qs     = (unsigned short*)alloc(64ull * 1024 * 128 * 2);
  unsigned short* kbuf   = (unsigned short*)alloc(64ull * 1024 * 128 * 2);
  unsigned short* vt     = (unsigned short*)alloc(64ull * 128 * 1024 * 2);
  unsigned short* vbf    = (unsigned short*)alloc(16384ull * 512 * 2);
  unsigned short* ctx    = (unsigned short*)alloc(16384ull * 512 * 2);

  k_convert_x<<<4096, 256, 0, stream>>>(x, x_bf);
  k_transpose_bf<<<(1536 * 64) / 256, 256, 0, stream>>>(w_qkv, wT_qkv, 1536);
  k_transpose_bf<<<(512 * 64) / 256, 256, 0, stream>>>(w_out, wT_out, 512);
  k_gemm<0><<<128 * 12, 256, 0, stream>>>(x_bf, wT_qkv, b_qkv, mask, nullptr, nullptr,
                                          qs, kbuf, vbf, vt, nullptr, 12, (128 * 12) / 8);
  k_attn<<<256, 512, 0, stream>>>(qs, kbuf, vt, mask, ctx);
  k_gemm<1><<<128 * 4, 256, 0, stream>>>(ctx, wT_out, b_out, mask, w_fsmn, vbf,
                                         nullptr, nullptr, nullptr, nullptr, out, 4, (128 * 4) / 8);
}